// Round 1
// baseline (238.337 us; speedup 1.0000x reference)
//
#include <hip/hip_runtime.h>

// SimpleGraphSAGE on MI355X.
// Structure exploited: dst = repeat(arange(N), DEG) -> edges for node i are
// src[i*DEG .. i*DEG+DEG), and every node has deg == DEG, so the
// row-normalized SpMM is a plain mean over 16 neighbor rows.
//
// layer(F, W, b, relu): out[i] = act( b + concat(F[i], mean_n F[src[i*16+n]]) @ W )
// Two launches: layer1 (relu) -> d_ws, layer2 -> d_out.

#define NN   100000
#define DEG  16
#define F    64
#define KDIM 128   // 2*F
#define NPB  32    // nodes per block (256 threads, 4 waves)
#define NPW  8     // nodes per wave

template<bool RELU>
__global__ __launch_bounds__(256)
void sage_layer(const float* __restrict__ feat,   // [NN, F]
                const float* __restrict__ W,      // [KDIM, F] row-major (k, j)
                const float* __restrict__ bias,   // [F]
                const int*   __restrict__ src,    // [NN*DEG]
                float*       __restrict__ out)    // [NN, F]
{
    __shared__ __align__(16) float W_lds[KDIM * F];   // 32 KB
    __shared__ __align__(16) float in_lds[NPB * KDIM]; // 16 KB

    const int tid  = threadIdx.x;
    const int lane = tid & 63;
    const int wave = tid >> 6;

    // Cooperative W stage: 8192 floats / 256 threads = 8 x float4 each.
    {
        const float4* Wv = (const float4*)W;
        float4*       Wl = (float4*)W_lds;
        #pragma unroll
        for (int i = 0; i < (KDIM * F / 4) / 256; ++i)
            Wl[tid + i * 256] = Wv[tid + i * 256];
    }

    const int node0 = blockIdx.x * NPB + wave * NPW;

    // Gather phase: build concat(self, mean-of-16-neighbors) rows in LDS.
    // Lane l handles feature column l; row loads are coalesced 256B.
    for (int m = 0; m < NPW; ++m) {
        const int node = node0 + m;
        if (node < NN) {
            const float self = feat[node * F + lane];
            const int* sp = src + node * DEG;
            float s = 0.f;
            #pragma unroll
            for (int n = 0; n < DEG; ++n) {
                const int idx = sp[n];          // uniform across lanes
                s += feat[idx * F + lane];
            }
            s *= (1.0f / DEG);
            const int row = wave * NPW + m;
            in_lds[row * KDIM + lane]     = self;
            in_lds[row * KDIM + F + lane] = s;
        }
    }
    __syncthreads();   // covers W_lds (cross-wave); in_lds rows are wave-private

    // Matmul phase: lane j computes output column j for this wave's 8 nodes.
    const int j = lane;
    float acc[NPW];
    const float bj = bias[j];
    #pragma unroll
    for (int m = 0; m < NPW; ++m) acc[m] = bj;

    const float* inb = &in_lds[wave * NPW * KDIM];
    #pragma unroll 1
    for (int k4 = 0; k4 < KDIM; k4 += 4) {
        // W reads: 64 consecutive lanes -> 2-way bank alias (free).
        const float w0 = W_lds[(k4 + 0) * F + j];
        const float w1 = W_lds[(k4 + 1) * F + j];
        const float w2 = W_lds[(k4 + 2) * F + j];
        const float w3 = W_lds[(k4 + 3) * F + j];
        #pragma unroll
        for (int m = 0; m < NPW; ++m) {
            // Broadcast ds_read_b128 (same addr across wave): conflict-free.
            const float4 v = *(const float4*)&inb[m * KDIM + k4];
            acc[m] = fmaf(v.x, w0, acc[m]);
            acc[m] = fmaf(v.y, w1, acc[m]);
            acc[m] = fmaf(v.z, w2, acc[m]);
            acc[m] = fmaf(v.w, w3, acc[m]);
        }
    }

    #pragma unroll
    for (int m = 0; m < NPW; ++m) {
        const int node = node0 + m;
        if (node < NN) {
            float r = acc[m];
            if (RELU) r = fmaxf(r, 0.f);
            out[node * F + j] = r;   // coalesced 256B store
        }
    }
}

extern "C" void kernel_launch(void* const* d_in, const int* in_sizes, int n_in,
                              void* d_out, int out_size, void* d_ws, size_t ws_size,
                              hipStream_t stream) {
    const float* x   = (const float*)d_in[0];
    const float* W1  = (const float*)d_in[1];
    const float* b1  = (const float*)d_in[2];
    const float* W2  = (const float*)d_in[3];
    const float* b2  = (const float*)d_in[4];
    const int*   src = (const int*)d_in[5];
    // d_in[6] = dst, unused: dst[e] == e / DEG by construction.

    float* h   = (float*)d_ws;    // [NN * F] fp32 = 25.6 MB
    float* out = (float*)d_out;

    const int blocks = (NN + NPB - 1) / NPB;   // 3125
    sage_layer<true ><<<blocks, 256, 0, stream>>>(x, W1, b1, src, h);
    sage_layer<false><<<blocks, 256, 0, stream>>>(h,  W2, b2, src, out);
}